// Round 7
// baseline (3131.720 us; speedup 1.0000x reference)
//
#include <hip/hip_runtime.h>
#include <hip/hip_bf16.h>

// Encoder: e = embed[x]; q = LSTM_q(e); k = LSTM_k(e); A = q @ k^T (per batch)
// B=32, T=512, D=512, NUM_TOKENS=14.
//
// R7: tag-embedded dataflow sync. h words stored as u32 (bf16(h)<<16 | (t+1));
// consumers poll the data itself until tags match -> no flags, no store drain,
// no publish hop. Max-skew safety: reaching step t requires everyone's h(t-1),
// which requires everyone finished reading h(t-2) -> 2-phase buffer never
// overwritten while readable. h staged once into LDS per WG (dedupes the 2x
// redundant per-wave loads of R6). 2 syncthreads/step total.

#define TB 32
#define TT 512
#define TD 512
#define NTOK 14

typedef __attribute__((ext_vector_type(8))) short short8;
typedef __attribute__((ext_vector_type(4))) float f32x4;
typedef __attribute__((ext_vector_type(4))) unsigned int u32x4;

__device__ __forceinline__ float fsigmoid(float v) { return 1.f / (1.f + __expf(-v)); }
__device__ __forceinline__ float ftanh(float v) {
    float a = fabsf(v);
    float e = __expf(-2.f * a);
    float r = (1.f - e) / (1.f + e);
    return copysignf(r, v);
}
__device__ __forceinline__ unsigned short f2bf(float f) {
    __hip_bfloat16 h = __float2bfloat16(f);
    return __builtin_bit_cast(unsigned short, h);
}

// coherent 16B load (bypass L1/L2 -> reads the coherent point, never stale)
__device__ __forceinline__ u32x4 load16_coh(const unsigned int* p) {
    u32x4 r;
    asm volatile("global_load_dwordx4 %0, %1, off sc0 sc1" : "=v"(r) : "v"(p));
    return r;
}
// coherent 4B store (write-through; fire-and-forget)
__device__ __forceinline__ void store4_coh(unsigned int* p, unsigned int v) {
    asm volatile("global_store_dword %0, %1, off sc0 sc1" :: "v"(p), "v"(v) : "memory");
}

// ---- pre_tab[l][tok][2048] = embed[tok] @ W_ih_l^T + b_ih_l + b_hh_l ----
__global__ __launch_bounds__(256) void pre_tab_kernel(
    const float* __restrict__ embed,
    const float* __restrict__ Wih_q, const float* __restrict__ bih_q, const float* __restrict__ bhh_q,
    const float* __restrict__ Wih_k, const float* __restrict__ bih_k, const float* __restrict__ bhh_k,
    float* __restrict__ pre)
{
    int idx = blockIdx.x * 256 + threadIdx.x;   // 2*14*2048 = 57344 exactly
    int l = idx / (NTOK * 4 * TD);
    int r = idx % (NTOK * 4 * TD);
    int tok = r / (4 * TD), j = r % (4 * TD);
    const float* Wih = l ? Wih_k : Wih_q;
    float acc = l ? (bih_k[j] + bhh_k[j]) : (bih_q[j] + bhh_q[j]);
    const float4* e4 = (const float4*)(embed + (size_t)tok * TD);
    const float4* w4 = (const float4*)(Wih + (size_t)j * TD);
    for (int t2 = 0; t2 < TD / 4; ++t2) {
        float4 e = e4[t2], w = w4[t2];
        acc += e.x * w.x + e.y * w.y + e.z * w.z + e.w * w.w;
    }
    pre[idx] = acc;
}

__global__ __launch_bounds__(256) void init_hbf(unsigned int* hbf) {
    int i = blockIdx.x * 256 + threadIdx.x;     // 2*2*32*512 = 65536
    if (i < 2 * 2 * TB * TD) hbf[i] = 0;        // tag 0 never matches (expected >= 1)
}

// ---- persistent LSTM: grid 128, wg>>6 = lstm l, (wg&63)*8 = dim chunk d0 ----
__global__ __launch_bounds__(256) void lstm_persist(
    const float* __restrict__ Whh_q, const float* __restrict__ Whh_k,
    const float* __restrict__ pre,
    const int* __restrict__ x,
    float* __restrict__ qout, float* __restrict__ kout,
    unsigned int* __restrict__ hbf)
{
    __shared__ unsigned short w_lds[32][512];   // 32 KB, 16B-chunk XOR swizzled
    __shared__ unsigned short h_lds[32][512];   // 32 KB, same swizzle (row = batch)
    __shared__ unsigned char  x_lds[TB * TT];   // 16 KB
    __shared__ float          pre_lds[NTOK][32];
    __shared__ float          g_lds[32][33];

    int wg  = blockIdx.x;
    int l   = wg >> 6;
    int wid = wg & 63;
    int d0  = wid << 3;
    int tid = threadIdx.x;
    int lane = tid & 63;
    int wv = tid >> 6;     // 4 waves
    int mt = wv & 1;       // batch tile for MFMA
    int nt = wv >> 1;      // gate-row tile for MFMA
    int bh = wv & 1;       // batch half for h loading
    int ch = wv >> 1;      // chunk half for h loading

    const float* Whh = l ? Whh_k : Whh_q;

    // stage W slice: LDS row r (=gate*8+dd) <- global row (r>>3)*TD + d0 + (r&7)
    // chunk = 8 bf16 (16 B); swizzle: store chunk c at position c ^ (r&7)
    {
        int r = tid >> 3;
        const float* src = Whh + (size_t)((r >> 3) * TD + d0 + (r & 7)) * TD;
        for (int i = 0; i < 8; ++i) {
            int c = (tid & 7) + 8 * i;
            float4 a = ((const float4*)src)[c * 2];
            float4 b = ((const float4*)src)[c * 2 + 1];
            unsigned short* dst = &w_lds[r][(c ^ (r & 7)) * 8];
            dst[0] = f2bf(a.x); dst[1] = f2bf(a.y); dst[2] = f2bf(a.z); dst[3] = f2bf(a.w);
            dst[4] = f2bf(b.x); dst[5] = f2bf(b.y); dst[6] = f2bf(b.z); dst[7] = f2bf(b.w);
        }
    }
    for (int i = tid; i < TB * TT; i += 256) x_lds[i] = (unsigned char)x[i];
    for (int i = tid; i < NTOK * 32; i += 256) {
        int tok = i >> 5, rr = i & 31;
        pre_lds[tok][rr] = pre[((size_t)l * NTOK + tok) * (4 * TD) + (rr >> 3) * TD + d0 + (rr & 7)];
    }
    __syncthreads();

    int b  = tid >> 3, dd = tid & 7;          // tail mapping
    float creg = 0.f;
    float* hist = l ? kout : qout;

    for (int t = 0; t < TT; ++t) {
        // ---- phase 1: poll-load h(t-1) (tagged), dedupe into h_lds ----
        if (t > 0) {
            const unsigned int e = (unsigned int)t;   // expected tag
            int b2 = bh * 16 + (lane & 15);
            const unsigned int* hb = hbf
                + (size_t)((((t - 1) & 1) * 2 + l) * TB + b2) * TD + ((lane >> 4) * 8);
            u32x4 A0[8], B0[8];
#pragma unroll
            for (int j = 0; j < 8; ++j) {
                int kk = ch * 8 + j;
                A0[j] = load16_coh(hb + kk * 32);
                B0[j] = load16_coh(hb + kk * 32 + 4);
            }
            asm volatile("s_waitcnt vmcnt(0)" ::: "memory");
            __builtin_amdgcn_sched_barrier(0);
#pragma unroll
            for (int j = 0; j < 8; ++j) {
                int kk = ch * 8 + j;
                for (;;) {
                    unsigned int bad =
                        ((A0[j].x ^ e) | (A0[j].y ^ e) | (A0[j].z ^ e) | (A0[j].w ^ e) |
                         (B0[j].x ^ e) | (B0[j].y ^ e) | (B0[j].z ^ e) | (B0[j].w ^ e)) & 0xffffu;
                    if (bad == 0) break;
                    A0[j] = load16_coh(hb + kk * 32);
                    B0[j] = load16_coh(hb + kk * 32 + 4);
                    asm volatile("s_waitcnt vmcnt(0)" ::: "memory");
                    __builtin_amdgcn_sched_barrier(0);
                }
                unsigned int w0 = (A0[j].x >> 16) | (A0[j].y & 0xffff0000u);
                unsigned int w1 = (A0[j].z >> 16) | (A0[j].w & 0xffff0000u);
                unsigned int w2 = (B0[j].x >> 16) | (B0[j].y & 0xffff0000u);
                unsigned int w3 = (B0[j].z >> 16) | (B0[j].w & 0xffff0000u);
                int cc = (lane >> 4) + kk * 4;
                u32x4* dst = (u32x4*)&h_lds[b2][(cc ^ (b2 & 7)) * 8];
                *dst = (u32x4){w0, w1, w2, w3};
            }
        }
        __syncthreads();   // h_lds ready (also separates h_lds writes from last iter's reads)

        // ---- phase 2: MFMA gates = h @ Wslice^T ----
        f32x4 acc = {0.f, 0.f, 0.f, 0.f};
        if (t > 0) {
            int rr = nt * 16 + (lane & 15);
            int b3 = mt * 16 + (lane & 15);
#pragma unroll
            for (int kk = 0; kk < 16; ++kk) {
                int c = kk * 4 + (lane >> 4);
                short8 a   = *(const short8*)&h_lds[b3][(c ^ (b3 & 7)) * 8];
                short8 bfr = *(const short8*)&w_lds[rr][(c ^ (rr & 7)) * 8];
                acc = __builtin_amdgcn_mfma_f32_16x16x32_bf16(a, bfr, acc, 0, 0, 0);
            }
        }
        // C/D: col(lane&15)->gate-row, row((lane>>4)*4+reg)->batch
        {
            int gr = nt * 16 + (lane & 15);
            int gb = mt * 16 + ((lane >> 4) << 2);
#pragma unroll
            for (int r2 = 0; r2 < 4; ++r2) g_lds[gr][gb + r2] = acc[r2];
        }
        __syncthreads();

        // ---- phase 3: pointwise tail; fire-and-forget tagged h store ----
        {
            int tok = x_lds[b * TT + t];
            float gi = g_lds[dd][b]      + pre_lds[tok][dd];
            float gf = g_lds[8 + dd][b]  + pre_lds[tok][8 + dd];
            float gg = g_lds[16 + dd][b] + pre_lds[tok][16 + dd];
            float go = g_lds[24 + dd][b] + pre_lds[tok][24 + dd];
            float i_ = fsigmoid(gi), f_ = fsigmoid(gf), g_ = ftanh(gg), o_ = fsigmoid(go);
            creg = f_ * creg + i_ * g_;
            float h = o_ * ftanh(creg);
            hist[((size_t)b * TT + t) * TD + d0 + dd] = h;   // plain (lazy L2)
            unsigned int word = ((unsigned int)f2bf(h) << 16) | (unsigned int)(t + 1);
            store4_coh(hbf + (size_t)(((t & 1) * 2 + l) * TB + b) * TD + d0 + dd, word);
        }
        // no drain, no flags: consumers poll the tagged data
    }
}

// ---- A[b] = q[b] @ k[b]^T, f32, 64x64 tile / WG, 4x4 per thread ----
__global__ __launch_bounds__(256) void qk_gemm(
    const float* __restrict__ q, const float* __restrict__ k, float* __restrict__ A)
{
    __shared__ float qs[64][68];
    __shared__ float ks[64][68];
    int b = blockIdx.y;
    int t0 = (blockIdx.x >> 3) * 64;
    int s0 = (blockIdx.x & 7) * 64;
    const float* qb = q + (size_t)b * TT * TD;
    const float* kb = k + (size_t)b * TT * TD;
    int tid = threadIdx.x;
    int ty = tid >> 4, tx = tid & 15;
    float accr[4][4] = {};
    for (int k0 = 0; k0 < TD; k0 += 64) {
        for (int i = tid; i < 64 * 16; i += 256) {
            int r = i >> 4, c4 = i & 15;
            ((float4*)&qs[r][0])[c4] = ((const float4*)(qb + (size_t)(t0 + r) * TD + k0))[c4];
            ((float4*)&ks[r][0])[c4] = ((const float4*)(kb + (size_t)(s0 + r) * TD + k0))[c4];
        }
        __syncthreads();
#pragma unroll 4
        for (int kk = 0; kk < 64; kk += 4) {
            float4 qv[4], kv[4];
#pragma unroll
            for (int i = 0; i < 4; ++i) qv[i] = *(const float4*)&qs[ty * 4 + i][kk];
#pragma unroll
            for (int j = 0; j < 4; ++j) kv[j] = *(const float4*)&ks[tx * 4 + j][kk];
#pragma unroll
            for (int i = 0; i < 4; ++i)
#pragma unroll
                for (int j = 0; j < 4; ++j)
                    accr[i][j] += qv[i].x * kv[j].x + qv[i].y * kv[j].y
                                + qv[i].z * kv[j].z + qv[i].w * kv[j].w;
        }
        __syncthreads();
    }
    for (int i = 0; i < 4; ++i)
        for (int j = 0; j < 4; ++j)
            A[(size_t)b * TT * TT + (size_t)(t0 + ty * 4 + i) * TT + (s0 + tx * 4 + j)] = accr[i][j];
}

extern "C" void kernel_launch(void* const* d_in, const int* in_sizes, int n_in,
                              void* d_out, int out_size, void* d_ws, size_t ws_size,
                              hipStream_t stream)
{
    const int*   x      = (const int*)d_in[0];
    const float* embed  = (const float*)d_in[1];
    const float* Wih_q  = (const float*)d_in[2];
    const float* Whh_q  = (const float*)d_in[3];
    const float* bih_q  = (const float*)d_in[4];
    const float* bhh_q  = (const float*)d_in[5];
    const float* Wih_k  = (const float*)d_in[6];
    const float* Whh_k  = (const float*)d_in[7];
    const float* bih_k  = (const float*)d_in[8];
    const float* bhh_k  = (const float*)d_in[9];

    float* ws   = (float*)d_ws;
    float* q    = ws;                                   // 8388608 f
    float* kbuf = q + (size_t)TB * TT * TD;             // 8388608 f
    float* pre  = kbuf + (size_t)TB * TT * TD;          // 57344 f
    unsigned int* hbf = (unsigned int*)(pre + 2 * NTOK * 4 * TD);  // 65536 u32

    init_hbf<<<256, 256, 0, stream>>>(hbf);
    pre_tab_kernel<<<224, 256, 0, stream>>>(embed, Wih_q, bih_q, bhh_q,
                                            Wih_k, bih_k, bhh_k, pre);
    lstm_persist<<<128, 256, 0, stream>>>(Whh_q, Whh_k, pre, x, q, kbuf, hbf);
    dim3 g(64, 32);
    qk_gemm<<<g, 256, 0, stream>>>(q, kbuf, (float*)d_out);
}